// Round 2
// baseline (429.843 us; speedup 1.0000x reference)
//
#include <hip/hip_runtime.h>
#include <hip/hip_bf16.h>
#include <math.h>

// ---------- types ----------
typedef __bf16 bf16_t;
typedef __bf16 bf16x8 __attribute__((ext_vector_type(8)));
typedef __bf16 bf16x4 __attribute__((ext_vector_type(4)));
typedef float  f32x4  __attribute__((ext_vector_type(4)));

#define B_ 4
#define S_ 4096
#define D_ 1024
#define N_ 256
#define M_ (B_*S_)   // 16384

// fast activations: v_exp_f32 + v_rcp_f32 (~1 ulp each, plenty for bf16 out)
__device__ __forceinline__ float fsig(float x){
    return __builtin_amdgcn_rcpf(1.0f + __expf(-x));
}
__device__ __forceinline__ float ftanh(float x){
    return 1.0f - 2.0f*__builtin_amdgcn_rcpf(1.0f + __expf(2.0f*x));
}

// async global->LDS, 16B per lane (dest = wave-uniform base + lane*16, linear)
__device__ __forceinline__ void gload_lds16(const void* g, void* l){
    __builtin_amdgcn_global_load_lds(
        (const __attribute__((address_space(1))) unsigned int*)g,
        (__attribute__((address_space(3))) unsigned int*)l, 16, 0, 0);
}

// ---------- all weight transposes in one launch ----------
struct TJobs {
    const float* in[7];
    bf16_t*      out[7];
    int R[7];
    int C[7];
};

__global__ void transpose_all(TJobs j){
    int z = blockIdx.z;
    int R = j.R[z], C = j.C[z];
    int c0 = blockIdx.x*32, r0 = blockIdx.y*32;
    if (c0 >= C || r0 >= R) return;
    __shared__ float tile[32][33];
    int tx = threadIdx.x, ty = threadIdx.y;       // x:0..31, y:0..7
    const float* in = j.in[z];
    bf16_t* out = j.out[z];
    #pragma unroll
    for (int i=0;i<32;i+=8)
        tile[ty+i][tx] = in[(size_t)(r0+ty+i)*C + (c0+tx)];
    __syncthreads();
    #pragma unroll
    for (int i=0;i<32;i+=8)
        out[(size_t)(c0+ty+i)*R + (r0+tx)] = (bf16_t)tile[tx][ty+i];
}

// ---------- LayerNorm: x f32 [M][D] -> h bf16 ----------
__global__ void ln_kernel(const float* __restrict__ x, const float* __restrict__ gw,
                          const float* __restrict__ bw, bf16_t* __restrict__ h){
    int row = blockIdx.x;
    int t = threadIdx.x;                           // 256 threads, 4 elems each
    float4 v = ((const float4*)(x + (size_t)row*D_))[t];
    float s = v.x+v.y+v.z+v.w;
    float q = v.x*v.x+v.y*v.y+v.z*v.z+v.w*v.w;
    #pragma unroll
    for (int o=1;o<64;o<<=1){ s += __shfl_xor(s,o,64); q += __shfl_xor(q,o,64); }
    __shared__ float sw[4], sq[4];
    int wid = t>>6;
    if ((t&63)==0){ sw[wid]=s; sq[wid]=q; }
    __syncthreads();
    s = sw[0]+sw[1]+sw[2]+sw[3];
    q = sq[0]+sq[1]+sq[2]+sq[3];
    float mu = s*(1.0f/D_);
    float rs = rsqrtf(q*(1.0f/D_) - mu*mu + 1e-5f);
    float4 gv = ((const float4*)gw)[t];
    float4 bv = ((const float4*)bw)[t];
    bf16x4 o4;
    o4[0] = (bf16_t)((v.x-mu)*rs*gv.x + bv.x);
    o4[1] = (bf16_t)((v.y-mu)*rs*gv.y + bv.y);
    o4[2] = (bf16_t)((v.z-mu)*rs*gv.z + bv.z);
    o4[3] = (bf16_t)((v.w-mu)*rs*gv.w + bv.w);
    *(bf16x4*)(h + (size_t)row*D_ + t*4) = o4;
}

// ---------- depthwise conv1d k=3 pad=1 along S ----------
__global__ void conv_kernel(const bf16_t* __restrict__ h, const float* __restrict__ w,
                            const float* __restrict__ mb, bf16_t* __restrict__ mix){
    int idx = blockIdx.x*256 + threadIdx.x;
    int g8  = idx & 127;
    int row = idx >> 7;                            // b*S + s
    int s   = row & (S_-1);
    int d0  = g8*8;
    const bf16_t* hr = h + (size_t)row*D_ + d0;
    bf16x8 cur = *(const bf16x8*)hr;
    bf16x8 prv, nxt;
    #pragma unroll
    for (int i=0;i<8;i++){ prv[i]=(bf16_t)0.0f; nxt[i]=(bf16_t)0.0f; }
    if (s > 0)      prv = *(const bf16x8*)(hr - D_);
    if (s < S_-1)   nxt = *(const bf16x8*)(hr + D_);
    bf16x8 ov;
    #pragma unroll
    for (int i=0;i<8;i++){
        int d = d0+i;
        float o = (float)prv[i]*w[d*3] + (float)cur[i]*w[d*3+1] + (float)nxt[i]*w[d*3+2] + mb[d];
        ov[i] = (bf16_t)o;
    }
    *(bf16x8*)(mix + (size_t)row*D_ + d0) = ov;
}

// ---------- 256x256 MFMA GEMM: BK=32, 8 waves, LDS dbuf 64KB, counted vmcnt ----------
struct Epi {
    const float *b0,*b1,*b2,*b3,*b4;
    bf16_t *u, *g, *z;
    bf16_t *xs, *dc, *sel;
    const bf16_t *gbuf, *ubuf;
    const float *resid;
    float *outp;
};

#define WAITV4() asm volatile("s_waitcnt vmcnt(4)" ::: "memory")
#define WAITV0() asm volatile("s_waitcnt vmcnt(0)" ::: "memory")
#define CFENCE() asm volatile("" ::: "memory")
#define BARR()   __builtin_amdgcn_s_barrier()

template<int MODE>
__global__ __launch_bounds__(512,2)
void gemm256(const bf16_t* __restrict__ A, const bf16_t* __restrict__ Bt,
             int K, Epi e){
    extern __shared__ __align__(16) char lds[];
    const int TILE = 16384;                 // bytes per 256x32 bf16 tile
    int t = threadIdx.x;
    int wave = t>>6, lane = t&63;
    int wm = (wave>>2)*128;                 // 2 wave-rows x 128
    int wn = (wave&3)*64;                   // 4 wave-cols x 64
    int lm = lane&15, quad = lane>>4;
    int m0 = blockIdx.x*256, n0 = blockIdx.y*256;
    int NT = K>>5;

    int srow = t>>2;
    int scol = (t&3)*8;
    const bf16_t* gA = A  + (size_t)(m0+srow)*K + scol;
    const bf16_t* gB = Bt + (size_t)(n0+srow)*K + scol;

    auto stage = [&](int kt, int buf){
        const bf16_t* a = gA + kt*32;
        const bf16_t* b = gB + kt*32;
        char* da = lds + buf*TILE + t*16;
        char* db = lds + 32768 + buf*TILE + t*16;
        gload_lds16(a,                  da);
        gload_lds16(a + (size_t)128*K,  da + 8192);
        gload_lds16(b,                  db);
        gload_lds16(b + (size_t)128*K,  db + 8192);
    };

    int raBase = (wm+lm)*64 + quad*16;
    int rbBase = (wn+lm)*64 + quad*16;

    f32x4 acc[8][4];
    #pragma unroll
    for (int i=0;i<8;i++)
        #pragma unroll
        for (int j=0;j<4;j++)
            #pragma unroll
            for (int r=0;r<4;r++) acc[i][j][r]=0.0f;

    bf16x8 aF[8], bF[4];

    stage(0,0);
    stage(1,1);
    WAITV4();
    BARR();

    for (int kt=0; kt<NT; ++kt){
        int buf = kt&1;
        const char* pa = lds + buf*TILE + raBase;
        const char* pb = lds + 32768 + buf*TILE + rbBase;

        #pragma unroll
        for (int i=0;i<4;i++) aF[i] = *(const bf16x8*)(pa + i*1024);
        #pragma unroll
        for (int j=0;j<4;j++) bF[j] = *(const bf16x8*)(pb + j*1024);
        BARR();
        asm volatile("s_waitcnt lgkmcnt(0)" ::: "memory");
        __builtin_amdgcn_sched_barrier(0);
        __builtin_amdgcn_s_setprio(1);
        #pragma unroll
        for (int i=0;i<4;i++)
            #pragma unroll
            for (int j=0;j<4;j++)
                acc[i][j] = __builtin_amdgcn_mfma_f32_16x16x32_bf16(aF[i], bF[j], acc[i][j], 0,0,0);
        __builtin_amdgcn_s_setprio(0);
        __builtin_amdgcn_sched_barrier(0);
        BARR();

        #pragma unroll
        for (int i=0;i<4;i++) aF[4+i] = *(const bf16x8*)(pa + (4+i)*1024);
        BARR();
        asm volatile("s_waitcnt lgkmcnt(0)" ::: "memory");
        __builtin_amdgcn_sched_barrier(0);
        __builtin_amdgcn_s_setprio(1);
        #pragma unroll
        for (int i=0;i<4;i++)
            #pragma unroll
            for (int j=0;j<4;j++)
                acc[4+i][j] = __builtin_amdgcn_mfma_f32_16x16x32_bf16(aF[4+i], bF[j], acc[4+i][j], 0,0,0);
        __builtin_amdgcn_s_setprio(0);
        __builtin_amdgcn_sched_barrier(0);
        BARR();

        if (kt+2 < NT){
            CFENCE();
            stage(kt+2, buf);
            WAITV4();
            BARR();
        } else if (kt+1 < NT){
            WAITV0();
            BARR();
        }
    }
    __syncthreads();

    if (MODE==0 || MODE==1){
        const float* bp = e.b0; int cbase = 0; bf16_t* dst = 0; int width = D_;
        bool ut = true;
        if (MODE==0){
            ut = (n0 < 1280);
            if (n0 < 1024){ bp=e.b0; cbase=n0; dst=e.u; width=D_; }
            else if (n0 < 1792){
                int sub=(n0-1024)>>8;
                bp  = sub==0? e.b1 : sub==1? e.b2 : e.b3;
                dst = sub==0? e.xs : sub==1? e.dc : e.sel;
                cbase = 0; width = N_;
            } else { bp=e.b4; cbase=n0-1792; dst=e.g; width=D_; }
        } else {
            bp = e.b0; cbase = n0; width = D_;
        }
        bf16_t* Tb = (bf16_t*)lds;
        #pragma unroll
        for (int h=0; h<4; h++){
            if (h) __syncthreads();
            if (wm == (h>>1)*128){
                int ib = (h&1)*4;
                #pragma unroll
                for (int ii=0;ii<4;ii++){
                    #pragma unroll
                    for (int j=0;j<4;j++){
                        float bv = bp[(MODE==0?cbase:n0) + wn + j*16 + lm];
                        #pragma unroll
                        for (int r=0;r<4;r++){
                            float v = acc[ib+ii][j][r] + bv;
                            if (MODE==0) v = ut ? ftanh(v) : fsig(v);
                            Tb[(ii*16+quad*4+r)*264 + wn + j*16 + lm] = (bf16_t)v;
                        }
                    }
                }
            }
            __syncthreads();
            if (MODE==0){
                #pragma unroll
                for (int it=0; it<4; it++){
                    int idx = it*512 + t;
                    int row = idx>>5, c8 = idx&31;
                    bf16x8 v = *(const bf16x8*)&Tb[row*264 + c8*8];
                    *(bf16x8*)&dst[(size_t)(m0 + h*64 + row)*width + cbase + c8*8] = v;
                }
            } else {
                #pragma unroll
                for (int it=0; it<4; it++){
                    int idx = it*512 + t;
                    int row = idx>>5, c8 = idx&31;
                    bf16x8 y = *(const bf16x8*)&Tb[row*264 + c8*8];
                    size_t gi = (size_t)(m0 + h*64 + row)*D_ + n0 + c8*8;
                    bf16x8 gv = *(const bf16x8*)&e.gbuf[gi];
                    bf16x8 uv = *(const bf16x8*)&e.ubuf[gi];
                    bf16x8 o;
                    #pragma unroll
                    for (int q=0;q<8;q++){
                        float gf = (float)gv[q];
                        o[q] = (bf16_t)(gf*(float)y[q] + (1.0f-gf)*(float)uv[q]);
                    }
                    *(bf16x8*)&e.z[gi] = o;
                }
            }
        }
    } else {
        float* T = (float*)lds;
        #pragma unroll
        for (int pZ=0; pZ<8; pZ++){
            if (pZ) __syncthreads();
            if (wm == (pZ>>2)*128){
                int ib = (pZ&3)*2;
                #pragma unroll
                for (int ii=0;ii<2;ii++){
                    #pragma unroll
                    for (int j=0;j<4;j++)
                        #pragma unroll
                        for (int r=0;r<4;r++)
                            T[(ii*16+quad*4+r)*260 + wn + j*16 + lm] = acc[ib+ii][j][r];
                }
            }
            __syncthreads();
            #pragma unroll
            for (int it=0; it<4; it++){
                int idx = it*512 + t;
                int row = idx>>6, c4 = idx&63;
                f32x4 v = *(const f32x4*)&T[row*260 + c4*4];
                size_t gi = (size_t)(m0 + pZ*32 + row)*D_ + n0 + c4*4;
                float4 res = *(const float4*)&e.resid[gi];
                float4 bb  = *(const float4*)&e.b0[n0 + c4*4];
                float4 o;
                o.x = v[0]+res.x+bb.x; o.y = v[1]+res.y+bb.y;
                o.z = v[2]+res.z+bb.z; o.w = v[3]+res.w+bb.w;
                *(float4*)&e.outp[gi] = o;
            }
        }
    }
}

// ---------- chunked affine scan: state = d*state + (1-d)*x (bf16 in, bf16 out) ----------
__global__ void scan_p1(const bf16_t* __restrict__ dc, const bf16_t* __restrict__ xs,
                        float* __restrict__ aggA, float* __restrict__ aggB){
    int bc = blockIdx.x;            // b*64 + chunk
    int b = bc>>6, ch = bc&63;
    int n = threadIdx.x;
    size_t base = ((size_t)b*S_ + ch*64)*N_ + n;
    float A = 1.0f, Bc = 0.0f;
    for (int t=0;t<64;t++){
        float d = (float)dc[base + (size_t)t*N_];
        float x = (float)xs[base + (size_t)t*N_];
        A  = d*A;
        Bc = d*Bc + (1.0f-d)*x;
    }
    aggA[(size_t)bc*N_+n]=A; aggB[(size_t)bc*N_+n]=Bc;
}

__global__ void scan_p2(const float* __restrict__ aggA, const float* __restrict__ aggB,
                        float* __restrict__ pre){
    int b = blockIdx.x, n = threadIdx.x;
    float s = 0.0f;
    for (int ch=0; ch<64; ch++){
        size_t i = ((size_t)b*64+ch)*N_+n;
        pre[i] = s;
        s = aggA[i]*s + aggB[i];
    }
}

__global__ void scan_p3(const bf16_t* __restrict__ dc, const bf16_t* __restrict__ xs,
                        const bf16_t* __restrict__ sel, const float* __restrict__ pre,
                        bf16_t* __restrict__ ss){
    int bc = blockIdx.x;
    int b = bc>>6, ch = bc&63;
    int n = threadIdx.x;
    size_t base = ((size_t)b*S_ + ch*64)*N_ + n;
    float s = pre[(size_t)bc*N_+n];
    for (int t=0;t<64;t++){
        size_t i = base + (size_t)t*N_;
        float d = (float)dc[i], x = (float)xs[i];
        s = d*s + (1.0f-d)*x;
        ss[i] = (bf16_t)((float)sel[i]*s);
    }
}

// ---------- launch ----------
extern "C" void kernel_launch(void* const* d_in, const int* in_sizes, int n_in,
                              void* d_out, int out_size, void* d_ws, size_t ws_size,
                              hipStream_t stream){
    const float* x    = (const float*)d_in[0];
    const float* ln_g = (const float*)d_in[1];
    const float* ln_b = (const float*)d_in[2];
    const float* mixw = (const float*)d_in[3];
    const float* mixb = (const float*)d_in[4];
    const float* Wi   = (const float*)d_in[5];
    const float* bi   = (const float*)d_in[6];
    const float* Wsin = (const float*)d_in[7];
    const float* bsin = (const float*)d_in[8];
    const float* Wd   = (const float*)d_in[9];
    const float* bd   = (const float*)d_in[10];
    const float* Wsel = (const float*)d_in[11];
    const float* bsel = (const float*)d_in[12];
    const float* Wso  = (const float*)d_in[13];
    const float* bso  = (const float*)d_in[14];
    const float* Wg   = (const float*)d_in[15];
    const float* bg   = (const float*)d_in[16];
    const float* Wout = (const float*)d_in[17];
    const float* bout = (const float*)d_in[18];
    float* out = (float*)d_out;

    char* p = (char*)d_ws;
    auto alloc = [&](size_t bytes)->char*{ char* r=p; p += (bytes+255)&~(size_t)255; return r; };
    bf16_t* hB    = (bf16_t*)alloc((size_t)M_*D_*2);
    bf16_t* mixB  = (bf16_t*)alloc((size_t)M_*D_*2);
    bf16_t* uB    = (bf16_t*)alloc((size_t)M_*D_*2);
    bf16_t* gB    = (bf16_t*)alloc((size_t)M_*D_*2);
    bf16_t* ssB   = (bf16_t*)alloc((size_t)M_*N_*2);
    bf16_t* xs    = (bf16_t*)alloc((size_t)M_*N_*2);
    bf16_t* dc    = (bf16_t*)alloc((size_t)M_*N_*2);
    bf16_t* sel   = (bf16_t*)alloc((size_t)M_*N_*2);
    bf16_t* WbigT = (bf16_t*)alloc((size_t)2816*1024*2);
    bf16_t* WsoT  = (bf16_t*)alloc(1024*256*2);
    bf16_t* WoutT = (bf16_t*)alloc(1024*1024*2);
    float*  aggA  = (float*)alloc((size_t)4*64*256*4);
    float*  aggB  = (float*)alloc((size_t)4*64*256*4);
    float*  pre   = (float*)alloc((size_t)4*64*256*4);
    bf16_t* zB = mixB;

    TJobs tj;
    tj.in[0]=Wi;   tj.out[0]=WbigT;            tj.R[0]=1024; tj.C[0]=1024;
    tj.in[1]=Wsin; tj.out[1]=WbigT+1024*1024;  tj.R[1]=1024; tj.C[1]=256;
    tj.in[2]=Wd;   tj.out[2]=WbigT+1280*1024;  tj.R[2]=1024; tj.C[2]=256;
    tj.in[3]=Wsel; tj.out[3]=WbigT+1536*1024;  tj.R[3]=1024; tj.C[3]=256;
    tj.in[4]=Wg;   tj.out[4]=WbigT+(size_t)1792*1024; tj.R[4]=1024; tj.C[4]=1024;
    tj.in[5]=Wso;  tj.out[5]=WsoT;             tj.R[5]=256;  tj.C[5]=1024;
    tj.in[6]=Wout; tj.out[6]=WoutT;            tj.R[6]=1024; tj.C[6]=1024;
    transpose_all<<<dim3(32,32,7), dim3(32,8), 0, stream>>>(tj);

    ln_kernel  <<<M_, 256, 0, stream>>>(x, ln_g, ln_b, hB);
    conv_kernel<<<M_*128/256, 256, 0, stream>>>(hB, mixw, mixb, mixB);

    Epi e0 = {};
    e0.b0=bi; e0.b1=bsin; e0.b2=bd; e0.b3=bsel; e0.b4=bg;
    e0.u=uB; e0.g=gB; e0.xs=xs; e0.dc=dc; e0.sel=sel;
    gemm256<0><<<dim3(M_/256, 11), 512, 65536, stream>>>(mixB, WbigT, 1024, e0);

    scan_p1<<<4*64, 256, 0, stream>>>(dc, xs, aggA, aggB);
    scan_p2<<<4,    256, 0, stream>>>(aggA, aggB, pre);
    scan_p3<<<4*64, 256, 0, stream>>>(dc, xs, sel, pre, ssB);

    Epi e1 = {};
    e1.b0=bso; e1.gbuf=gB; e1.ubuf=uB; e1.z=zB;
    gemm256<1><<<dim3(M_/256, 4), 512, 65536, stream>>>(ssB, WsoT, 256, e1);

    Epi e2 = {};
    e2.b0=bout; e2.resid=x; e2.outp=out;
    gemm256<2><<<dim3(M_/256, 4), 512, 65536, stream>>>(zB, WoutT, 1024, e2);
}

// Round 3
// 415.397 us; speedup vs baseline: 1.0348x; 1.0348x over previous
//
#include <hip/hip_runtime.h>
#include <hip/hip_bf16.h>
#include <math.h>

// ---------- types ----------
typedef __bf16 bf16_t;
typedef __bf16 bf16x8 __attribute__((ext_vector_type(8)));
typedef __bf16 bf16x4 __attribute__((ext_vector_type(4)));
typedef float  f32x4  __attribute__((ext_vector_type(4)));

#define B_ 4
#define S_ 4096
#define D_ 1024
#define N_ 256
#define M_ (B_*S_)   // 16384

// fast activations: v_exp_f32 + v_rcp_f32 (~1 ulp each, plenty for bf16 out)
__device__ __forceinline__ float fsig(float x){
    return __builtin_amdgcn_rcpf(1.0f + __expf(-x));
}
__device__ __forceinline__ float ftanh(float x){
    return 1.0f - 2.0f*__builtin_amdgcn_rcpf(1.0f + __expf(2.0f*x));
}

// async global->LDS, 16B per lane (dest = wave-uniform base + lane*16, linear)
__device__ __forceinline__ void gload_lds16(const void* g, void* l){
    __builtin_amdgcn_global_load_lds(
        (const __attribute__((address_space(1))) unsigned int*)g,
        (__attribute__((address_space(3))) unsigned int*)l, 16, 0, 0);
}

// ---------- all weight transposes in one launch ----------
struct TJobs {
    const float* in[7];
    bf16_t*      out[7];
    int R[7];
    int C[7];
};

__global__ void transpose_all(TJobs j){
    int z = blockIdx.z;
    int R = j.R[z], C = j.C[z];
    int c0 = blockIdx.x*32, r0 = blockIdx.y*32;
    if (c0 >= C || r0 >= R) return;
    __shared__ float tile[32][33];
    int tx = threadIdx.x, ty = threadIdx.y;       // x:0..31, y:0..7
    const float* in = j.in[z];
    bf16_t* out = j.out[z];
    #pragma unroll
    for (int i=0;i<32;i+=8)
        tile[ty+i][tx] = in[(size_t)(r0+ty+i)*C + (c0+tx)];
    __syncthreads();
    #pragma unroll
    for (int i=0;i<32;i+=8)
        out[(size_t)(c0+ty+i)*R + (r0+tx)] = (bf16_t)tile[tx][ty+i];
}

// ---------- LayerNorm: x f32 [M][D] -> h bf16 ----------
__global__ void ln_kernel(const float* __restrict__ x, const float* __restrict__ gw,
                          const float* __restrict__ bw, bf16_t* __restrict__ h){
    int row = blockIdx.x;
    int t = threadIdx.x;                           // 256 threads, 4 elems each
    float4 v = ((const float4*)(x + (size_t)row*D_))[t];
    float s = v.x+v.y+v.z+v.w;
    float q = v.x*v.x+v.y*v.y+v.z*v.z+v.w*v.w;
    #pragma unroll
    for (int o=1;o<64;o<<=1){ s += __shfl_xor(s,o,64); q += __shfl_xor(q,o,64); }
    __shared__ float sw[4], sq[4];
    int wid = t>>6;
    if ((t&63)==0){ sw[wid]=s; sq[wid]=q; }
    __syncthreads();
    s = sw[0]+sw[1]+sw[2]+sw[3];
    q = sq[0]+sq[1]+sq[2]+sq[3];
    float mu = s*(1.0f/D_);
    float rs = rsqrtf(q*(1.0f/D_) - mu*mu + 1e-5f);
    float4 gv = ((const float4*)gw)[t];
    float4 bv = ((const float4*)bw)[t];
    bf16x4 o4;
    o4[0] = (bf16_t)((v.x-mu)*rs*gv.x + bv.x);
    o4[1] = (bf16_t)((v.y-mu)*rs*gv.y + bv.y);
    o4[2] = (bf16_t)((v.z-mu)*rs*gv.z + bv.z);
    o4[3] = (bf16_t)((v.w-mu)*rs*gv.w + bv.w);
    *(bf16x4*)(h + (size_t)row*D_ + t*4) = o4;
}

// ---------- depthwise conv1d k=3 pad=1 along S ----------
__global__ void conv_kernel(const bf16_t* __restrict__ h, const float* __restrict__ w,
                            const float* __restrict__ mb, bf16_t* __restrict__ mix){
    int idx = blockIdx.x*256 + threadIdx.x;
    int g8  = idx & 127;
    int row = idx >> 7;                            // b*S + s
    int s   = row & (S_-1);
    int d0  = g8*8;
    const bf16_t* hr = h + (size_t)row*D_ + d0;
    bf16x8 cur = *(const bf16x8*)hr;
    bf16x8 prv, nxt;
    #pragma unroll
    for (int i=0;i<8;i++){ prv[i]=(bf16_t)0.0f; nxt[i]=(bf16_t)0.0f; }
    if (s > 0)      prv = *(const bf16x8*)(hr - D_);
    if (s < S_-1)   nxt = *(const bf16x8*)(hr + D_);
    bf16x8 ov;
    #pragma unroll
    for (int i=0;i<8;i++){
        int d = d0+i;
        float o = (float)prv[i]*w[d*3] + (float)cur[i]*w[d*3+1] + (float)nxt[i]*w[d*3+2] + mb[d];
        ov[i] = (bf16_t)o;
    }
    *(bf16x8*)(mix + (size_t)row*D_ + d0) = ov;
}

// ---------- 256x256 MFMA GEMM: BK=32, 8 waves, LDS dbuf 64KB ----------
// K-loop: barrier-free tile body (12 ds_read_b128 + 32 MFMA, compiler-scheduled
// so wave-level LDS/MFMA overlap happens), then exactly 2 sync points per tile:
//   lgkmcnt(0)+barrier (reads of buf done) -> stage(kt+2, buf) ->
//   vmcnt(4) (tile kt+1 landed; kt+2's 4 loads stay in flight) -> barrier.
struct Epi {
    const float *b0,*b1,*b2,*b3,*b4;
    bf16_t *u, *g, *z;
    bf16_t *xs, *dc, *sel;
    const bf16_t *gbuf, *ubuf;
    const float *resid;
    float *outp;
};

#define WAITV4()  asm volatile("s_waitcnt vmcnt(4)" ::: "memory")
#define WAITV0()  asm volatile("s_waitcnt vmcnt(0)" ::: "memory")
#define WAITLGK0() asm volatile("s_waitcnt lgkmcnt(0)" ::: "memory")
#define CFENCE()  asm volatile("" ::: "memory")
#define BARR()    __builtin_amdgcn_s_barrier()

template<int MODE>
__global__ __launch_bounds__(512,2)
void gemm256(const bf16_t* __restrict__ A, const bf16_t* __restrict__ Bt,
             int K, Epi e){
    extern __shared__ __align__(16) char lds[];
    const int TILE = 16384;                 // bytes per 256x32 bf16 tile
    int t = threadIdx.x;
    int wave = t>>6, lane = t&63;
    int wm = (wave>>2)*128;                 // 2 wave-rows x 128
    int wn = (wave&3)*64;                   // 4 wave-cols x 64
    int lm = lane&15, quad = lane>>4;
    int m0 = blockIdx.x*256, n0 = blockIdx.y*256;
    int NT = K>>5;

    int srow = t>>2;
    int scol = (t&3)*8;
    const bf16_t* gA = A  + (size_t)(m0+srow)*K + scol;
    const bf16_t* gB = Bt + (size_t)(n0+srow)*K + scol;

    auto stage = [&](int kt, int buf){
        const bf16_t* a = gA + kt*32;
        const bf16_t* b = gB + kt*32;
        char* da = lds + buf*TILE + t*16;
        char* db = lds + 32768 + buf*TILE + t*16;
        gload_lds16(a,                  da);
        gload_lds16(a + (size_t)128*K,  da + 8192);
        gload_lds16(b,                  db);
        gload_lds16(b + (size_t)128*K,  db + 8192);
    };

    int raBase = (wm+lm)*64 + quad*16;
    int rbBase = (wn+lm)*64 + quad*16;

    f32x4 acc[8][4];
    #pragma unroll
    for (int i=0;i<8;i++)
        #pragma unroll
        for (int j=0;j<4;j++)
            #pragma unroll
            for (int r=0;r<4;r++) acc[i][j][r]=0.0f;

    bf16x8 aF[8], bF[4];

    stage(0,0);
    stage(1,1);
    WAITV4();
    BARR();
    CFENCE();

    for (int kt=0; kt<NT; ++kt){
        int buf = kt&1;
        const char* pa = lds + buf*TILE + raBase;
        const char* pb = lds + 32768 + buf*TILE + rbBase;

        // ---- barrier-free body: all fragment reads + 32 MFMA ----
        #pragma unroll
        for (int j=0;j<4;j++) bF[j] = *(const bf16x8*)(pb + j*1024);
        #pragma unroll
        for (int i=0;i<8;i++) aF[i] = *(const bf16x8*)(pa + i*1024);

        __builtin_amdgcn_s_setprio(1);
        #pragma unroll
        for (int i=0;i<8;i++)           // i-major: aF[4..7]'s latency hides under early MFMAs
            #pragma unroll
            for (int j=0;j<4;j++)
                acc[i][j] = __builtin_amdgcn_mfma_f32_16x16x32_bf16(aF[i], bF[j], acc[i][j], 0,0,0);
        __builtin_amdgcn_s_setprio(0);

        // ---- tile boundary: 2 sync points ----
        WAITLGK0();                      // all LDS reads of buf retired (guards raw s_barrier)
        BARR();                          // every wave done reading buf
        CFENCE();
        if (kt+2 < NT){
            stage(kt+2, buf);            // refill just-retired buffer
            WAITV4();                    // tile kt+1 landed; kt+2's 4 loads in flight
            BARR();
            CFENCE();
        } else if (kt+1 < NT){
            WAITV0();                    // tail drain
            BARR();
            CFENCE();
        }
    }
    __syncthreads();

    if (MODE==0 || MODE==1){
        const float* bp = e.b0; int cbase = 0; bf16_t* dst = 0; int width = D_;
        bool ut = true;
        if (MODE==0){
            ut = (n0 < 1280);
            if (n0 < 1024){ bp=e.b0; cbase=n0; dst=e.u; width=D_; }
            else if (n0 < 1792){
                int sub=(n0-1024)>>8;
                bp  = sub==0? e.b1 : sub==1? e.b2 : e.b3;
                dst = sub==0? e.xs : sub==1? e.dc : e.sel;
                cbase = 0; width = N_;
            } else { bp=e.b4; cbase=n0-1792; dst=e.g; width=D_; }
        } else {
            bp = e.b0; cbase = n0; width = D_;
        }
        bf16_t* Tb = (bf16_t*)lds;
        #pragma unroll
        for (int h=0; h<4; h++){
            if (h) __syncthreads();
            if (wm == (h>>1)*128){
                int ib = (h&1)*4;
                #pragma unroll
                for (int ii=0;ii<4;ii++){
                    #pragma unroll
                    for (int j=0;j<4;j++){
                        float bv = bp[(MODE==0?cbase:n0) + wn + j*16 + lm];
                        #pragma unroll
                        for (int r=0;r<4;r++){
                            float v = acc[ib+ii][j][r] + bv;
                            if (MODE==0) v = ut ? ftanh(v) : fsig(v);
                            Tb[(ii*16+quad*4+r)*264 + wn + j*16 + lm] = (bf16_t)v;
                        }
                    }
                }
            }
            __syncthreads();
            if (MODE==0){
                #pragma unroll
                for (int it=0; it<4; it++){
                    int idx = it*512 + t;
                    int row = idx>>5, c8 = idx&31;
                    bf16x8 v = *(const bf16x8*)&Tb[row*264 + c8*8];
                    *(bf16x8*)&dst[(size_t)(m0 + h*64 + row)*width + cbase + c8*8] = v;
                }
            } else {
                #pragma unroll
                for (int it=0; it<4; it++){
                    int idx = it*512 + t;
                    int row = idx>>5, c8 = idx&31;
                    bf16x8 y = *(const bf16x8*)&Tb[row*264 + c8*8];
                    size_t gi = (size_t)(m0 + h*64 + row)*D_ + n0 + c8*8;
                    bf16x8 gv = *(const bf16x8*)&e.gbuf[gi];
                    bf16x8 uv = *(const bf16x8*)&e.ubuf[gi];
                    bf16x8 o;
                    #pragma unroll
                    for (int q=0;q<8;q++){
                        float gf = (float)gv[q];
                        o[q] = (bf16_t)(gf*(float)y[q] + (1.0f-gf)*(float)uv[q]);
                    }
                    *(bf16x8*)&e.z[gi] = o;
                }
            }
        }
    } else {
        float* T = (float*)lds;
        #pragma unroll
        for (int pZ=0; pZ<8; pZ++){
            if (pZ) __syncthreads();
            if (wm == (pZ>>2)*128){
                int ib = (pZ&3)*2;
                #pragma unroll
                for (int ii=0;ii<2;ii++){
                    #pragma unroll
                    for (int j=0;j<4;j++)
                        #pragma unroll
                        for (int r=0;r<4;r++)
                            T[(ii*16+quad*4+r)*260 + wn + j*16 + lm] = acc[ib+ii][j][r];
                }
            }
            __syncthreads();
            #pragma unroll
            for (int it=0; it<4; it++){
                int idx = it*512 + t;
                int row = idx>>6, c4 = idx&63;
                f32x4 v = *(const f32x4*)&T[row*260 + c4*4];
                size_t gi = (size_t)(m0 + pZ*32 + row)*D_ + n0 + c4*4;
                float4 res = *(const float4*)&e.resid[gi];
                float4 bb  = *(const float4*)&e.b0[n0 + c4*4];
                float4 o;
                o.x = v[0]+res.x+bb.x; o.y = v[1]+res.y+bb.y;
                o.z = v[2]+res.z+bb.z; o.w = v[3]+res.w+bb.w;
                *(float4*)&e.outp[gi] = o;
            }
        }
    }
}

// ---------- chunked affine scan: state = d*state + (1-d)*x (bf16 in, bf16 out) ----------
__global__ void scan_p1(const bf16_t* __restrict__ dc, const bf16_t* __restrict__ xs,
                        float* __restrict__ aggA, float* __restrict__ aggB){
    int bc = blockIdx.x;            // b*64 + chunk
    int b = bc>>6, ch = bc&63;
    int n = threadIdx.x;
    size_t base = ((size_t)b*S_ + ch*64)*N_ + n;
    float A = 1.0f, Bc = 0.0f;
    for (int t=0;t<64;t++){
        float d = (float)dc[base + (size_t)t*N_];
        float x = (float)xs[base + (size_t)t*N_];
        A  = d*A;
        Bc = d*Bc + (1.0f-d)*x;
    }
    aggA[(size_t)bc*N_+n]=A; aggB[(size_t)bc*N_+n]=Bc;
}

__global__ void scan_p2(const float* __restrict__ aggA, const float* __restrict__ aggB,
                        float* __restrict__ pre){
    int b = blockIdx.x, n = threadIdx.x;
    float s = 0.0f;
    for (int ch=0; ch<64; ch++){
        size_t i = ((size_t)b*64+ch)*N_+n;
        pre[i] = s;
        s = aggA[i]*s + aggB[i];
    }
}

__global__ void scan_p3(const bf16_t* __restrict__ dc, const bf16_t* __restrict__ xs,
                        const bf16_t* __restrict__ sel, const float* __restrict__ pre,
                        bf16_t* __restrict__ ss){
    int bc = blockIdx.x;
    int b = bc>>6, ch = bc&63;
    int n = threadIdx.x;
    size_t base = ((size_t)b*S_ + ch*64)*N_ + n;
    float s = pre[(size_t)bc*N_+n];
    for (int t=0;t<64;t++){
        size_t i = base + (size_t)t*N_;
        float d = (float)dc[i], x = (float)xs[i];
        s = d*s + (1.0f-d)*x;
        ss[i] = (bf16_t)((float)sel[i]*s);
    }
}

// ---------- launch ----------
extern "C" void kernel_launch(void* const* d_in, const int* in_sizes, int n_in,
                              void* d_out, int out_size, void* d_ws, size_t ws_size,
                              hipStream_t stream){
    const float* x    = (const float*)d_in[0];
    const float* ln_g = (const float*)d_in[1];
    const float* ln_b = (const float*)d_in[2];
    const float* mixw = (const float*)d_in[3];
    const float* mixb = (const float*)d_in[4];
    const float* Wi   = (const float*)d_in[5];
    const float* bi   = (const float*)d_in[6];
    const float* Wsin = (const float*)d_in[7];
    const float* bsin = (const float*)d_in[8];
    const float* Wd   = (const float*)d_in[9];
    const float* bd   = (const float*)d_in[10];
    const float* Wsel = (const float*)d_in[11];
    const float* bsel = (const float*)d_in[12];
    const float* Wso  = (const float*)d_in[13];
    const float* bso  = (const float*)d_in[14];
    const float* Wg   = (const float*)d_in[15];
    const float* bg   = (const float*)d_in[16];
    const float* Wout = (const float*)d_in[17];
    const float* bout = (const float*)d_in[18];
    float* out = (float*)d_out;

    char* p = (char*)d_ws;
    auto alloc = [&](size_t bytes)->char*{ char* r=p; p += (bytes+255)&~(size_t)255; return r; };
    bf16_t* hB    = (bf16_t*)alloc((size_t)M_*D_*2);
    bf16_t* mixB  = (bf16_t*)alloc((size_t)M_*D_*2);
    bf16_t* uB    = (bf16_t*)alloc((size_t)M_*D_*2);
    bf16_t* gB    = (bf16_t*)alloc((size_t)M_*D_*2);
    bf16_t* ssB   = (bf16_t*)alloc((size_t)M_*N_*2);
    bf16_t* xs    = (bf16_t*)alloc((size_t)M_*N_*2);
    bf16_t* dc    = (bf16_t*)alloc((size_t)M_*N_*2);
    bf16_t* sel   = (bf16_t*)alloc((size_t)M_*N_*2);
    bf16_t* WbigT = (bf16_t*)alloc((size_t)2816*1024*2);
    bf16_t* WsoT  = (bf16_t*)alloc(1024*256*2);
    bf16_t* WoutT = (bf16_t*)alloc(1024*1024*2);
    float*  aggA  = (float*)alloc((size_t)4*64*256*4);
    float*  aggB  = (float*)alloc((size_t)4*64*256*4);
    float*  pre   = (float*)alloc((size_t)4*64*256*4);
    bf16_t* zB = mixB;

    TJobs tj;
    tj.in[0]=Wi;   tj.out[0]=WbigT;            tj.R[0]=1024; tj.C[0]=1024;
    tj.in[1]=Wsin; tj.out[1]=WbigT+1024*1024;  tj.R[1]=1024; tj.C[1]=256;
    tj.in[2]=Wd;   tj.out[2]=WbigT+1280*1024;  tj.R[2]=1024; tj.C[2]=256;
    tj.in[3]=Wsel; tj.out[3]=WbigT+1536*1024;  tj.R[3]=1024; tj.C[3]=256;
    tj.in[4]=Wg;   tj.out[4]=WbigT+(size_t)1792*1024; tj.R[4]=1024; tj.C[4]=1024;
    tj.in[5]=Wso;  tj.out[5]=WsoT;             tj.R[5]=256;  tj.C[5]=1024;
    tj.in[6]=Wout; tj.out[6]=WoutT;            tj.R[6]=1024; tj.C[6]=1024;
    transpose_all<<<dim3(32,32,7), dim3(32,8), 0, stream>>>(tj);

    ln_kernel  <<<M_, 256, 0, stream>>>(x, ln_g, ln_b, hB);
    conv_kernel<<<M_*128/256, 256, 0, stream>>>(hB, mixw, mixb, mixB);

    Epi e0 = {};
    e0.b0=bi; e0.b1=bsin; e0.b2=bd; e0.b3=bsel; e0.b4=bg;
    e0.u=uB; e0.g=gB; e0.xs=xs; e0.dc=dc; e0.sel=sel;
    gemm256<0><<<dim3(M_/256, 11), 512, 65536, stream>>>(mixB, WbigT, 1024, e0);

    scan_p1<<<4*64, 256, 0, stream>>>(dc, xs, aggA, aggB);
    scan_p2<<<4,    256, 0, stream>>>(aggA, aggB, pre);
    scan_p3<<<4*64, 256, 0, stream>>>(dc, xs, sel, pre, ssB);

    Epi e1 = {};
    e1.b0=bso; e1.gbuf=gB; e1.ubuf=uB; e1.z=zB;
    gemm256<1><<<dim3(M_/256, 4), 512, 65536, stream>>>(ssB, WsoT, 256, e1);

    Epi e2 = {};
    e2.b0=bout; e2.resid=x; e2.outp=out;
    gemm256<2><<<dim3(M_/256, 4), 512, 65536, stream>>>(zB, WoutT, 1024, e2);
}

// Round 5
// 404.662 us; speedup vs baseline: 1.0622x; 1.0265x over previous
//
#include <hip/hip_runtime.h>
#include <hip/hip_bf16.h>
#include <math.h>

// ---------- types ----------
typedef __bf16 bf16_t;
typedef __bf16 bf16x8 __attribute__((ext_vector_type(8)));
typedef __bf16 bf16x4 __attribute__((ext_vector_type(4)));
typedef float  f32x4  __attribute__((ext_vector_type(4)));

#define B_ 4
#define S_ 4096
#define D_ 1024
#define N_ 256
#define M_ (B_*S_)   // 16384

// fast activations: v_exp_f32 + v_rcp_f32 (~1 ulp each, plenty for bf16 out)
__device__ __forceinline__ float fsig(float x){
    return __builtin_amdgcn_rcpf(1.0f + __expf(-x));
}
__device__ __forceinline__ float ftanh(float x){
    return 1.0f - 2.0f*__builtin_amdgcn_rcpf(1.0f + __expf(2.0f*x));
}

// async global->LDS, 16B per lane (dest = wave-uniform base + lane*16, linear)
__device__ __forceinline__ void gload_lds16(const void* g, void* l){
    __builtin_amdgcn_global_load_lds(
        (const __attribute__((address_space(1))) unsigned int*)g,
        (__attribute__((address_space(3))) unsigned int*)l, 16, 0, 0);
}

// ---------- all weight transposes in one launch ----------
struct TJobs {
    const float* in[7];
    bf16_t*      out[7];
    int R[7];
    int C[7];
};

__global__ void transpose_all(TJobs j){
    int z = blockIdx.z;
    int R = j.R[z], C = j.C[z];
    int c0 = blockIdx.x*32, r0 = blockIdx.y*32;
    if (c0 >= C || r0 >= R) return;
    __shared__ float tile[32][33];
    int tx = threadIdx.x, ty = threadIdx.y;       // x:0..31, y:0..7
    const float* in = j.in[z];
    bf16_t* out = j.out[z];
    #pragma unroll
    for (int i=0;i<32;i+=8)
        tile[ty+i][tx] = in[(size_t)(r0+ty+i)*C + (c0+tx)];
    __syncthreads();
    #pragma unroll
    for (int i=0;i<32;i+=8)
        out[(size_t)(c0+ty+i)*R + (r0+tx)] = (bf16_t)tile[tx][ty+i];
}

// ---------- LayerNorm: x f32 [M][D] -> h bf16 ----------
__global__ void ln_kernel(const float* __restrict__ x, const float* __restrict__ gw,
                          const float* __restrict__ bw, bf16_t* __restrict__ h){
    int row = blockIdx.x;
    int t = threadIdx.x;                           // 256 threads, 4 elems each
    float4 v = ((const float4*)(x + (size_t)row*D_))[t];
    float s = v.x+v.y+v.z+v.w;
    float q = v.x*v.x+v.y*v.y+v.z*v.z+v.w*v.w;
    #pragma unroll
    for (int o=1;o<64;o<<=1){ s += __shfl_xor(s,o,64); q += __shfl_xor(q,o,64); }
    __shared__ float sw[4], sq[4];
    int wid = t>>6;
    if ((t&63)==0){ sw[wid]=s; sq[wid]=q; }
    __syncthreads();
    s = sw[0]+sw[1]+sw[2]+sw[3];
    q = sq[0]+sq[1]+sq[2]+sq[3];
    float mu = s*(1.0f/D_);
    float rs = rsqrtf(q*(1.0f/D_) - mu*mu + 1e-5f);
    float4 gv = ((const float4*)gw)[t];
    float4 bv = ((const float4*)bw)[t];
    bf16x4 o4;
    o4[0] = (bf16_t)((v.x-mu)*rs*gv.x + bv.x);
    o4[1] = (bf16_t)((v.y-mu)*rs*gv.y + bv.y);
    o4[2] = (bf16_t)((v.z-mu)*rs*gv.z + bv.z);
    o4[3] = (bf16_t)((v.w-mu)*rs*gv.w + bv.w);
    *(bf16x4*)(h + (size_t)row*D_ + t*4) = o4;
}

// ---------- depthwise conv1d k=3 pad=1 along S ----------
__global__ void conv_kernel(const bf16_t* __restrict__ h, const float* __restrict__ w,
                            const float* __restrict__ mb, bf16_t* __restrict__ mix){
    int idx = blockIdx.x*256 + threadIdx.x;
    int g8  = idx & 127;
    int row = idx >> 7;                            // b*S + s
    int s   = row & (S_-1);
    int d0  = g8*8;
    const bf16_t* hr = h + (size_t)row*D_ + d0;
    bf16x8 cur = *(const bf16x8*)hr;
    bf16x8 prv, nxt;
    #pragma unroll
    for (int i=0;i<8;i++){ prv[i]=(bf16_t)0.0f; nxt[i]=(bf16_t)0.0f; }
    if (s > 0)      prv = *(const bf16x8*)(hr - D_);
    if (s < S_-1)   nxt = *(const bf16x8*)(hr + D_);
    bf16x8 ov;
    #pragma unroll
    for (int i=0;i<8;i++){
        int d = d0+i;
        float o = (float)prv[i]*w[d*3] + (float)cur[i]*w[d*3+1] + (float)nxt[i]*w[d*3+2] + mb[d];
        ov[i] = (bf16_t)o;
    }
    *(bf16x8*)(mix + (size_t)row*D_ + d0) = ov;
}

// ---------- 128x256 MFMA GEMM: BK=32, 8 waves, 48KB LDS dbuf, 2 blocks/CU ----------
// Per wave: 64x64 output (acc 64 VGPR), aF[4]+bF[4] frags (32 VGPR) -> <=128 total
// so TWO blocks co-reside per CU (4 waves/SIMD): one block's LDS read phase
// overlaps the other block's MFMA phase (the single-block 256^2 design serialized).
// XCD swizzle: consecutive remapped blocks share the B panel -> same-XCD L2 hits.
struct Epi {
    const float *b0,*b1,*b2,*b3,*b4;
    bf16_t *u, *g, *z;
    bf16_t *xs, *dc, *sel;
    const bf16_t *gbuf, *ubuf;
    const float *resid;
    float *outp;
};

#define WAITV3()  asm volatile("s_waitcnt vmcnt(3)" ::: "memory")
#define WAITV0()  asm volatile("s_waitcnt vmcnt(0)" ::: "memory")
#define WAITLGK0() asm volatile("s_waitcnt lgkmcnt(0)" ::: "memory")
#define CFENCE()  asm volatile("" ::: "memory")
#define BARR()    __builtin_amdgcn_s_barrier()

template<int MODE>
__global__ __launch_bounds__(512,4)
void gemm128(const bf16_t* __restrict__ A, const bf16_t* __restrict__ Bt,
             int K, Epi e){
    extern __shared__ __align__(16) char lds[];
    const int ATILE = 8192;                 // 128x32 bf16
    const int BTILE = 16384;                // 256x32 bf16
    int t = threadIdx.x;
    int wave = t>>6, lane = t&63;
    int wm = (wave>>2)*64;                  // 2 wave-rows x 64
    int wn = (wave&3)*64;                   // 4 wave-cols x 64
    int lm = lane&15, quad = lane>>4;

    // bijective XCD swizzle (all grids have nwg % 8 == 0)
    int flat = blockIdx.y*gridDim.x + blockIdx.x;
    int nwg  = gridDim.x*gridDim.y;
    int wg   = (flat&7)*(nwg>>3) + (flat>>3);
    int m0 = (wg & 127)*128;                // gridDim.x == 128 always
    int n0 = (wg >> 7)*256;
    int NT = K>>5;

    const bf16_t* gA = A  + (size_t)(m0 + (t>>2))*K + (t&3)*8;
    const bf16_t* gB = Bt + (size_t)(n0 + (t>>2))*K + (t&3)*8;

    auto stage = [&](int kt, int buf){
        const bf16_t* a = gA + kt*32;
        const bf16_t* b = gB + kt*32;
        char* da = lds + buf*ATILE + t*16;
        char* db = lds + 16384 + buf*BTILE + t*16;
        gload_lds16(a, da);                       // A rows 0..127
        gload_lds16(b, db);                       // B rows 0..127
        gload_lds16(b + (size_t)128*K, db + 8192);// B rows 128..255
    };

    int raBase = (wm+lm)*64 + quad*16;
    int rbBase = (wn+lm)*64 + quad*16;

    f32x4 acc[4][4];
    #pragma unroll
    for (int i=0;i<4;i++)
        #pragma unroll
        for (int j=0;j<4;j++)
            #pragma unroll
            for (int r=0;r<4;r++) acc[i][j][r]=0.0f;

    bf16x8 aF[4], bF[4];

    stage(0,0);
    stage(1,1);
    WAITV3();                    // tile 0 landed; tile 1's 3 loads in flight
    BARR();
    CFENCE();

    for (int kt=0; kt<NT; ++kt){
        int buf = kt&1;
        const char* pa = lds + buf*ATILE + raBase;
        const char* pb = lds + 16384 + buf*BTILE + rbBase;

        #pragma unroll
        for (int j=0;j<4;j++) bF[j] = *(const bf16x8*)(pb + j*1024);
        #pragma unroll
        for (int i=0;i<4;i++) aF[i] = *(const bf16x8*)(pa + i*1024);

        #pragma unroll
        for (int i=0;i<4;i++)
            #pragma unroll
            for (int j=0;j<4;j++)
                acc[i][j] = __builtin_amdgcn_mfma_f32_16x16x32_bf16(aF[i], bF[j], acc[i][j], 0,0,0);

        WAITLGK0();                      // all LDS reads of buf retired
        BARR();
        CFENCE();
        if (kt+2 < NT){
            stage(kt+2, buf);            // refill just-retired buffer
            WAITV3();                    // tile kt+1 landed; kt+2's 3 in flight
            BARR();
            CFENCE();
        } else if (kt+1 < NT){
            WAITV0();                    // tail drain
            BARR();
            CFENCE();
        }
    }
    __syncthreads();

    // ---- epilogue: retile through LDS for coalesced global I/O ----
    // acc layout: row = wm + i*16 + quad*4 + r, col = wn + j*16 + lm (128x256 tile)
    if (MODE==0 || MODE==1){
        const float* bp = e.b0; int cbase = 0; bf16_t* dst = 0; int width = D_;
        bool ut = true;
        if (MODE==0){
            ut = (n0 < 1280);
            if (n0 < 1024){ bp=e.b0; cbase=n0; dst=e.u; width=D_; }
            else if (n0 < 1792){
                int sub=(n0-1024)>>8;
                bp  = sub==0? e.b1 : sub==1? e.b2 : e.b3;
                dst = sub==0? e.xs : sub==1? e.dc : e.sel;
                cbase = 0; width = N_;
            } else { bp=e.b4; cbase=n0-1792; dst=e.g; width=D_; }
        } else {
            bp = e.b0; cbase = n0; width = D_;
        }
        bf16_t* Tb = (bf16_t*)lds;
        #pragma unroll
        for (int h=0; h<2; h++){                      // 64-row bands, stride 264
            if (h) __syncthreads();
            if (wm == h*64){
                #pragma unroll
                for (int ii=0;ii<4;ii++){
                    #pragma unroll
                    for (int j=0;j<4;j++){
                        float bv = bp[(MODE==0?cbase:n0) + wn + j*16 + lm];
                        #pragma unroll
                        for (int r=0;r<4;r++){
                            float v = acc[ii][j][r] + bv;
                            if (MODE==0) v = ut ? ftanh(v) : fsig(v);
                            Tb[(ii*16+quad*4+r)*264 + wn + j*16 + lm] = (bf16_t)v;
                        }
                    }
                }
            }
            __syncthreads();
            if (MODE==0){
                #pragma unroll
                for (int it=0; it<4; it++){
                    int idx = it*512 + t;
                    int row = idx>>5, c8 = idx&31;
                    bf16x8 v = *(const bf16x8*)&Tb[row*264 + c8*8];
                    *(bf16x8*)&dst[(size_t)(m0 + h*64 + row)*width + cbase + c8*8] = v;
                }
            } else {
                #pragma unroll
                for (int it=0; it<4; it++){
                    int idx = it*512 + t;
                    int row = idx>>5, c8 = idx&31;
                    bf16x8 y = *(const bf16x8*)&Tb[row*264 + c8*8];
                    size_t gi = (size_t)(m0 + h*64 + row)*D_ + n0 + c8*8;
                    bf16x8 gv = *(const bf16x8*)&e.gbuf[gi];
                    bf16x8 uv = *(const bf16x8*)&e.ubuf[gi];
                    bf16x8 o;
                    #pragma unroll
                    for (int q=0;q<8;q++){
                        float gf = (float)gv[q];
                        o[q] = (bf16_t)(gf*(float)y[q] + (1.0f-gf)*(float)uv[q]);
                    }
                    *(bf16x8*)&e.z[gi] = o;
                }
            }
        }
    } else {
        float* T = (float*)lds;
        #pragma unroll
        for (int pZ=0; pZ<4; pZ++){                   // 32-row bands, stride 260
            if (pZ) __syncthreads();
            if (wm == (pZ>>1)*64){
                int ib = (pZ&1)*2;
                #pragma unroll
                for (int ii=0;ii<2;ii++){
                    #pragma unroll
                    for (int j=0;j<4;j++)
                        #pragma unroll
                        for (int r=0;r<4;r++)
                            T[(ii*16+quad*4+r)*260 + wn + j*16 + lm] = acc[ib+ii][j][r];
                }
            }
            __syncthreads();
            #pragma unroll
            for (int it=0; it<4; it++){
                int idx = it*512 + t;
                int row = idx>>6, c4 = idx&63;
                f32x4 v = *(const f32x4*)&T[row*260 + c4*4];
                size_t gi = (size_t)(m0 + pZ*32 + row)*D_ + n0 + c4*4;
                float4 res = *(const float4*)&e.resid[gi];
                float4 bb  = *(const float4*)&e.b0[n0 + c4*4];
                float4 o;
                o.x = v[0]+res.x+bb.x; o.y = v[1]+res.y+bb.y;
                o.z = v[2]+res.z+bb.z; o.w = v[3]+res.w+bb.w;
                *(float4*)&e.outp[gi] = o;
            }
        }
    }
}

// ---------- chunked affine scan: state = d*state + (1-d)*x (bf16 in, bf16 out) ----------
__global__ void scan_p1(const bf16_t* __restrict__ dc, const bf16_t* __restrict__ xs,
                        float* __restrict__ aggA, float* __restrict__ aggB){
    int bc = blockIdx.x;            // b*64 + chunk
    int b = bc>>6, ch = bc&63;
    int n = threadIdx.x;
    size_t base = ((size_t)b*S_ + ch*64)*N_ + n;
    float A = 1.0f, Bc = 0.0f;
    for (int t=0;t<64;t++){
        float d = (float)dc[base + (size_t)t*N_];
        float x = (float)xs[base + (size_t)t*N_];
        A  = d*A;
        Bc = d*Bc + (1.0f-d)*x;
    }
    aggA[(size_t)bc*N_+n]=A; aggB[(size_t)bc*N_+n]=Bc;
}

__global__ void scan_p2(const float* __restrict__ aggA, const float* __restrict__ aggB,
                        float* __restrict__ pre){
    int b = blockIdx.x, n = threadIdx.x;
    float s = 0.0f;
    for (int ch=0; ch<64; ch++){
        size_t i = ((size_t)b*64+ch)*N_+n;
        pre[i] = s;
        s = aggA[i]*s + aggB[i];
    }
}

__global__ void scan_p3(const bf16_t* __restrict__ dc, const bf16_t* __restrict__ xs,
                        const bf16_t* __restrict__ sel, const float* __restrict__ pre,
                        bf16_t* __restrict__ ss){
    int bc = blockIdx.x;
    int b = bc>>6, ch = bc&63;
    int n = threadIdx.x;
    size_t base = ((size_t)b*S_ + ch*64)*N_ + n;
    float s = pre[(size_t)bc*N_+n];
    for (int t=0;t<64;t++){
        size_t i = base + (size_t)t*N_;
        float d = (float)dc[i], x = (float)xs[i];
        s = d*s + (1.0f-d)*x;
        ss[i] = (bf16_t)((float)sel[i]*s);
    }
}

// ---------- launch ----------
extern "C" void kernel_launch(void* const* d_in, const int* in_sizes, int n_in,
                              void* d_out, int out_size, void* d_ws, size_t ws_size,
                              hipStream_t stream){
    const float* x    = (const float*)d_in[0];
    const float* ln_g = (const float*)d_in[1];
    const float* ln_b = (const float*)d_in[2];
    const float* mixw = (const float*)d_in[3];
    const float* mixb = (const float*)d_in[4];
    const float* Wi   = (const float*)d_in[5];
    const float* bi   = (const float*)d_in[6];
    const float* Wsin = (const float*)d_in[7];
    const float* bsin = (const float*)d_in[8];
    const float* Wd   = (const float*)d_in[9];
    const float* bd   = (const float*)d_in[10];
    const float* Wsel = (const float*)d_in[11];
    const float* bsel = (const float*)d_in[12];
    const float* Wso  = (const float*)d_in[13];
    const float* bso  = (const float*)d_in[14];
    const float* Wg   = (const float*)d_in[15];
    const float* bg   = (const float*)d_in[16];
    const float* Wout = (const float*)d_in[17];
    const float* bout = (const float*)d_in[18];
    float* out = (float*)d_out;

    char* p = (char*)d_ws;
    auto alloc = [&](size_t bytes)->char*{ char* r=p; p += (bytes+255)&~(size_t)255; return r; };
    bf16_t* hB    = (bf16_t*)alloc((size_t)M_*D_*2);
    bf16_t* mixB  = (bf16_t*)alloc((size_t)M_*D_*2);
    bf16_t* uB    = (bf16_t*)alloc((size_t)M_*D_*2);
    bf16_t* gB    = (bf16_t*)alloc((size_t)M_*D_*2);
    bf16_t* ssB   = (bf16_t*)alloc((size_t)M_*N_*2);
    bf16_t* xs    = (bf16_t*)alloc((size_t)M_*N_*2);
    bf16_t* dc    = (bf16_t*)alloc((size_t)M_*N_*2);
    bf16_t* sel   = (bf16_t*)alloc((size_t)M_*N_*2);
    bf16_t* WbigT = (bf16_t*)alloc((size_t)2816*1024*2);
    bf16_t* WsoT  = (bf16_t*)alloc(1024*256*2);
    bf16_t* WoutT = (bf16_t*)alloc(1024*1024*2);
    float*  aggA  = (float*)alloc((size_t)4*64*256*4);
    float*  aggB  = (float*)alloc((size_t)4*64*256*4);
    float*  pre   = (float*)alloc((size_t)4*64*256*4);
    bf16_t* zB = mixB;

    TJobs tj;
    tj.in[0]=Wi;   tj.out[0]=WbigT;            tj.R[0]=1024; tj.C[0]=1024;
    tj.in[1]=Wsin; tj.out[1]=WbigT+1024*1024;  tj.R[1]=1024; tj.C[1]=256;
    tj.in[2]=Wd;   tj.out[2]=WbigT+1280*1024;  tj.R[2]=1024; tj.C[2]=256;
    tj.in[3]=Wsel; tj.out[3]=WbigT+1536*1024;  tj.R[3]=1024; tj.C[3]=256;
    tj.in[4]=Wg;   tj.out[4]=WbigT+(size_t)1792*1024; tj.R[4]=1024; tj.C[4]=1024;
    tj.in[5]=Wso;  tj.out[5]=WsoT;             tj.R[5]=256;  tj.C[5]=1024;
    tj.in[6]=Wout; tj.out[6]=WoutT;            tj.R[6]=1024; tj.C[6]=1024;
    transpose_all<<<dim3(32,32,7), dim3(32,8), 0, stream>>>(tj);

    ln_kernel  <<<M_, 256, 0, stream>>>(x, ln_g, ln_b, hB);
    conv_kernel<<<M_*128/256, 256, 0, stream>>>(hB, mixw, mixb, mixB);

    Epi e0 = {};
    e0.b0=bi; e0.b1=bsin; e0.b2=bd; e0.b3=bsel; e0.b4=bg;
    e0.u=uB; e0.g=gB; e0.xs=xs; e0.dc=dc; e0.sel=sel;
    gemm128<0><<<dim3(M_/128, 11), 512, 49152, stream>>>(mixB, WbigT, 1024, e0);

    scan_p1<<<4*64, 256, 0, stream>>>(dc, xs, aggA, aggB);
    scan_p2<<<4,    256, 0, stream>>>(aggA, aggB, pre);
    scan_p3<<<4*64, 256, 0, stream>>>(dc, xs, sel, pre, ssB);

    Epi e1 = {};
    e1.b0=bso; e1.gbuf=gB; e1.ubuf=uB; e1.z=zB;
    gemm128<1><<<dim3(M_/128, 4), 512, 49152, stream>>>(ssB, WsoT, 256, e1);

    Epi e2 = {};
    e2.b0=bout; e2.resid=x; e2.outp=out;
    gemm128<2><<<dim3(M_/128, 4), 512, 49152, stream>>>(zB, WoutT, 1024, e2);
}